// Round 1
// 795.044 us; speedup vs baseline: 1.0570x; 1.0570x over previous
//
#include <hip/hip_runtime.h>

typedef __attribute__((ext_vector_type(8))) short short8;
typedef __attribute__((ext_vector_type(4))) float f32x4;

#define NW_MASK 511

__device__ __forceinline__ short f2bf(float f) {
  unsigned u = __builtin_bit_cast(unsigned, f);
  u = (u + 0x7fffu + ((u >> 16) & 1u)) >> 16;  // RNE
  return (short)u;
}

// ---------------------------------------------------------------------------
// Prep: gather rpb bias -> bias_f[6][64][64]; pre-transpose + frag-swizzle
// qkv_w (96x288) and proj_w (96x96) into MFMA B-fragment-linear bf16 layout:
// ws*[ (nt*3+ks)*64 + lane ][ j ] = W[ ks*32 + (lane>>4)*8 + j ][ nt*16 + (lane&15) ]
// ---------------------------------------------------------------------------
__global__ void prep_kernel(const float* __restrict__ qkv_w,
                            const float* __restrict__ proj_w,
                            const float* __restrict__ rpb,
                            const int* __restrict__ rel_index,
                            float* __restrict__ bias_f,
                            short* __restrict__ wsq,
                            short* __restrict__ wsp) {
  int idx = blockIdx.x * 256 + threadIdx.x;
  if (idx < 24576) {                       // 6*64*64 bias gather
    int h = idx >> 12;
    int rm = idx & 4095;
    bias_f[idx] = rpb[rel_index[rm] * 6 + h];
  }
  int i2 = idx - 24576;
  if (i2 >= 0 && i2 < 27648) {             // 18 ntiles * 3 ksteps * 64 * 8
    int j = i2 & 7;
    int lane = (i2 >> 3) & 63;
    int frag = i2 >> 9;
    int ks = frag % 3, nt = frag / 3;
    int k = ks * 32 + (lane >> 4) * 8 + j;
    int n = nt * 16 + (lane & 15);
    wsq[i2] = f2bf(qkv_w[k * 288 + n]);
  }
  int i3 = i2 - 27648;
  if (i3 >= 0 && i3 < 9216) {              // 6 ntiles * 3 ksteps * 64 * 8
    int j = i3 & 7;
    int lane = (i3 >> 3) & 63;
    int frag = i3 >> 9;
    int ks = frag % 3, nt = frag / 3;
    int k = ks * 32 + (lane >> 4) * 8 + j;
    int n = nt * 16 + (lane & 15);
    wsp[i3] = f2bf(proj_w[k * 96 + n]);
  }
}

// ---------------------------------------------------------------------------
// Fused window attention: one block per window (8192), 256 threads (4 waves).
// LDS cut to 52736 B -> 3 blocks/CU (was 2). The softmax P round-trip and the
// concat buffer are WAVE-PRIVATE (wave w only ever touches rows w*16..w*16+15
// in both), so they share one buffer `pc` and need NO barriers — within-wave
// LDS write->read ordering is handled by compiler-inserted lgkmcnt waits.
// Only one __syncthreads() remains (after phase 1: qk/vT are cross-wave).
// ---------------------------------------------------------------------------
__global__ __launch_bounds__(256) void winattn_kernel(
    const float* __restrict__ x, const float* __restrict__ mask,
    const float* __restrict__ qkv_b, const float* __restrict__ proj_b,
    const float* __restrict__ bias_f, const short* __restrict__ wsq,
    const short* __restrict__ wsp, float* __restrict__ out) {
  // qk: rows 64, cols 0..95 = q (pre-scaled by 0.25), 96..191 = k; stride 200
  __shared__ __align__(16) short qk[64 * 200];   // 25600 B
  __shared__ __align__(16) short vT[96 * 72];    // v transposed [h*16+d][j], 13824 B
  __shared__ __align__(16) short pc[64 * 104];   // P round-trip + concat, wave-private rows, 13312 B

  const int b = blockIdx.x;
  const int t = threadIdx.x;
  const int w = t >> 6;        // wave id = m-tile in phases 2/3
  const int l = t & 63;
  const int lm = l & 15;
  const int quad = l >> 4;

  // ---- Phase 1: qkv = x @ Wqkv + b  (A-frags in regs, B-frags from ws) ----
  short8 afr[4][3];
#pragma unroll
  for (int mt = 0; mt < 4; ++mt)
#pragma unroll
    for (int ks = 0; ks < 3; ++ks) {
      const float* xp = x + ((size_t)b * 64 + mt * 16 + lm) * 96 + ks * 32 + quad * 8;
      const float4 u0 = *(const float4*)xp;
      const float4 u1 = *(const float4*)(xp + 4);
      short8 a;
      a[0] = f2bf(u0.x); a[1] = f2bf(u0.y); a[2] = f2bf(u0.z); a[3] = f2bf(u0.w);
      a[4] = f2bf(u1.x); a[5] = f2bf(u1.y); a[6] = f2bf(u1.z); a[7] = f2bf(u1.w);
      afr[mt][ks] = a;
    }

  const short8* wsq8 = (const short8*)wsq;
  // 36 work units = 18 ntiles x 2 m-halves, 9 per wave (balanced)
  for (int u = w * 9; u < w * 9 + 9; ++u) {
    const int nt = u >> 1, mh = (u & 1) * 2;
    short8 bfr[3];
#pragma unroll
    for (int ks = 0; ks < 3; ++ks) bfr[ks] = wsq8[(nt * 3 + ks) * 64 + l];
    const int c = nt * 16 + lm;
    const float bq = qkv_b[c];
    const float sc = (c < 96) ? 0.25f : 1.0f;  // q pre-scale, hd^-0.5 exact
#pragma unroll
    for (int mi = 0; mi < 2; ++mi) {
      const int mt = mh + mi;
      f32x4 acc = {bq, bq, bq, bq};
#pragma unroll
      for (int ks = 0; ks < 3; ++ks)
        acc = __builtin_amdgcn_mfma_f32_16x16x32_bf16(afr[mt][ks], bfr[ks], acc, 0, 0, 0);
#pragma unroll
      for (int i = 0; i < 4; ++i) {
        const int r = mt * 16 + quad * 4 + i;   // C-layout: row = quad*4+reg
        const short v = f2bf(acc[i] * sc);
        if (c < 192) qk[r * 200 + c] = v;
        else vT[(c - 192) * 72 + r] = v;
      }
    }
  }
  __syncthreads();   // the ONLY barrier: qk (k-cols) and vT are read cross-wave

  // ---- Phase 2: per-head attention, O accumulates in regs; no barriers ----
  f32x4 oacc[6];
  const int rbase = w * 16 + quad * 4;
  const float* maskp = mask + (size_t)(b & NW_MASK) * 4096;
#pragma unroll
  for (int h = 0; h < 6; ++h) {
    const f32x4 z4 = {0.f, 0.f, 0.f, 0.f};
    short8 qa = {0, 0, 0, 0, 0, 0, 0, 0};     // k>=16 zero-padded
    if (quad < 2)
      qa = *(const short8*)&qk[(w * 16 + lm) * 200 + h * 16 + quad * 8];
    f32x4 lac[4];
#pragma unroll
    for (int nt = 0; nt < 4; ++nt) {
      short8 kb = {0, 0, 0, 0, 0, 0, 0, 0};
      if (quad < 2)
        kb = *(const short8*)&qk[(nt * 16 + lm) * 200 + 96 + h * 16 + quad * 8];
      lac[nt] = __builtin_amdgcn_mfma_f32_16x16x32_bf16(qa, kb, z4, 0, 0, 0);
    }
    // bias + mask + softmax (row r lives in the 16-lane group sharing quad)
#pragma unroll
    for (int i = 0; i < 4; ++i) {
      const int r = rbase + i;
      const float* bp = bias_f + ((h * 64 + r) << 6);
      const float* mp = maskp + (r << 6);
      float lv[4];
      float mx = -3.0e38f;
#pragma unroll
      for (int nt = 0; nt < 4; ++nt) {
        const int j = nt * 16 + lm;
        lv[nt] = lac[nt][i] + bp[j] + mp[j];
        mx = fmaxf(mx, lv[nt]);
      }
      mx = fmaxf(mx, __shfl_xor(mx, 1));
      mx = fmaxf(mx, __shfl_xor(mx, 2));
      mx = fmaxf(mx, __shfl_xor(mx, 4));
      mx = fmaxf(mx, __shfl_xor(mx, 8));
      float sm = 0.f;
#pragma unroll
      for (int nt = 0; nt < 4; ++nt) { lv[nt] = __expf(lv[nt] - mx); sm += lv[nt]; }
      sm += __shfl_xor(sm, 1);
      sm += __shfl_xor(sm, 2);
      sm += __shfl_xor(sm, 4);
      sm += __shfl_xor(sm, 8);
      const float inv = 1.0f / sm;
#pragma unroll
      for (int nt = 0; nt < 4; ++nt)
        pc[r * 104 + nt * 16 + lm] = f2bf(lv[nt] * inv);
    }
    // PV: O[r][d] += P[r][j] V[j][d], K=64 in 2 steps. Same-wave LDS
    // write->read: compiler inserts lgkmcnt, no barrier needed.
    f32x4 oa = {0.f, 0.f, 0.f, 0.f};
#pragma unroll
    for (int ks = 0; ks < 2; ++ks) {
      const short8 pa = *(const short8*)&pc[(w * 16 + lm) * 104 + ks * 32 + quad * 8];
      const short8 vb = *(const short8*)&vT[(h * 16 + lm) * 72 + ks * 32 + quad * 8];
      oa = __builtin_amdgcn_mfma_f32_16x16x32_bf16(pa, vb, oa, 0, 0, 0);
    }
    oacc[h] = oa;
  }

  // ---- Phase 3: out = concat(O) @ proj_w + b (concat reuses pc, wave-private) ----
#pragma unroll
  for (int h = 0; h < 6; ++h)
#pragma unroll
    for (int i = 0; i < 4; ++i)
      pc[(rbase + i) * 104 + h * 16 + lm] = f2bf(oacc[h][i]);

  short8 ca[3];
#pragma unroll
  for (int ks = 0; ks < 3; ++ks)
    ca[ks] = *(const short8*)&pc[(w * 16 + lm) * 104 + ks * 32 + quad * 8];

  const short8* wsp8 = (const short8*)wsp;
  float* outp = out + (size_t)b * 64 * 96;
#pragma unroll
  for (int nt = 0; nt < 6; ++nt) {
    short8 pw[3];
#pragma unroll
    for (int ks = 0; ks < 3; ++ks) pw[ks] = wsp8[(nt * 3 + ks) * 64 + l];
    const float bp = proj_b[nt * 16 + lm];
    f32x4 acc = {bp, bp, bp, bp};
#pragma unroll
    for (int ks = 0; ks < 3; ++ks)
      acc = __builtin_amdgcn_mfma_f32_16x16x32_bf16(ca[ks], pw[ks], acc, 0, 0, 0);
#pragma unroll
    for (int i = 0; i < 4; ++i)
      outp[(rbase + i) * 96 + nt * 16 + lm] = acc[i];
  }
}

extern "C" void kernel_launch(void* const* d_in, const int* in_sizes, int n_in,
                              void* d_out, int out_size, void* d_ws, size_t ws_size,
                              hipStream_t stream) {
  const float* x      = (const float*)d_in[0];
  const float* mask   = (const float*)d_in[1];
  const float* qkv_w  = (const float*)d_in[2];
  const float* qkv_b  = (const float*)d_in[3];
  const float* proj_w = (const float*)d_in[4];
  const float* proj_b = (const float*)d_in[5];
  const float* rpb    = (const float*)d_in[6];
  const int*   rel    = (const int*)d_in[7];

  float* bias_f = (float*)d_ws;                               // 98304 B
  short* wsq    = (short*)((char*)d_ws + 98304);              // 55296 B
  short* wsp    = (short*)((char*)d_ws + 98304 + 55296);      // 18432 B

  hipLaunchKernelGGL(prep_kernel, dim3(240), dim3(256), 0, stream,
                     qkv_w, proj_w, rpb, rel, bias_f, wsq, wsp);
  hipLaunchKernelGGL(winattn_kernel, dim3(8192), dim3(256), 0, stream,
                     x, mask, qkv_b, proj_b, bias_f, wsq, wsp, (float*)d_out);
}

// Round 2
// 771.695 us; speedup vs baseline: 1.0890x; 1.0303x over previous
//
#include <hip/hip_runtime.h>

typedef __attribute__((ext_vector_type(8))) short short8;
typedef __attribute__((ext_vector_type(4))) float f32x4;

#define NW_MASK 511

__device__ __forceinline__ short f2bf(float f) {
  unsigned u = __builtin_bit_cast(unsigned, f);
  u = (u + 0x7fffu + ((u >> 16) & 1u)) >> 16;  // RNE
  return (short)u;
}

__device__ __forceinline__ unsigned cvt_pk_bf16(float lo, float hi) {
  unsigned r;
  asm("v_cvt_pk_bf16_f32 %0, %1, %2" : "=v"(r) : "v"(lo), "v"(hi));
  return r;  // low 16 = bf16(lo), high 16 = bf16(hi), RNE
}

// ---------------------------------------------------------------------------
// Prep: gather rpb bias -> bias_f[6][64][64]; pre-transpose + frag-swizzle
// qkv_w (96x288) and proj_w (96x96) into MFMA B-fragment-linear bf16 layout:
// ws*[ (nt*3+ks)*64 + lane ][ j ] = W[ ks*32 + (lane>>4)*8 + j ][ nt*16 + (lane&15) ]
// ---------------------------------------------------------------------------
__global__ void prep_kernel(const float* __restrict__ qkv_w,
                            const float* __restrict__ proj_w,
                            const float* __restrict__ rpb,
                            const int* __restrict__ rel_index,
                            float* __restrict__ bias_f,
                            short* __restrict__ wsq,
                            short* __restrict__ wsp) {
  int idx = blockIdx.x * 256 + threadIdx.x;
  if (idx < 24576) {                       // 6*64*64 bias gather
    int h = idx >> 12;
    int rm = idx & 4095;
    bias_f[idx] = rpb[rel_index[rm] * 6 + h];
  }
  int i2 = idx - 24576;
  if (i2 >= 0 && i2 < 27648) {             // 18 ntiles * 3 ksteps * 64 * 8
    int j = i2 & 7;
    int lane = (i2 >> 3) & 63;
    int frag = i2 >> 9;
    int ks = frag % 3, nt = frag / 3;
    int k = ks * 32 + (lane >> 4) * 8 + j;
    int n = nt * 16 + (lane & 15);
    wsq[i2] = f2bf(qkv_w[k * 288 + n]);
  }
  int i3 = i2 - 27648;
  if (i3 >= 0 && i3 < 9216) {              // 6 ntiles * 3 ksteps * 64 * 8
    int j = i3 & 7;
    int lane = (i3 >> 3) & 63;
    int frag = i3 >> 9;
    int ks = frag % 3, nt = frag / 3;
    int k = ks * 32 + (lane >> 4) * 8 + j;
    int n = nt * 16 + (lane & 15);
    wsp[i3] = f2bf(proj_w[k * 96 + n]);
  }
}

// ---------------------------------------------------------------------------
// Fused window attention: one block per window (8192), 256 threads (4 waves).
// LDS = qk (25600) + vT (13824) = 39424 B -> 4 blocks/CU.
// QK^T is computed SWAPPED (S^T = mfma(K, Q)) so lane (quad,lm) holds
// S[row=w*16+lm][col=nt*16+quad*4+i]:
//   - bias/mask loads are float4 (col-contiguous); mask hoisted out of h-loop
//   - softmax reduce = 16 in-lane + 2 shuffles
//   - P written as packed u32 (cvt_pk_bf16) into the dead q-columns of qk
//     (wave-private rows; all 6 q B-frags preloaded to regs after the barrier)
// Concat (phase 3) also reuses the q-columns. Single __syncthreads() total.
// ---------------------------------------------------------------------------
__global__ __launch_bounds__(256, 4) void winattn_kernel(
    const float* __restrict__ x, const float* __restrict__ mask,
    const float* __restrict__ qkv_b, const float* __restrict__ proj_b,
    const float* __restrict__ bias_f, const short* __restrict__ wsq,
    const short* __restrict__ wsp, float* __restrict__ out) {
  // qk: rows 64, cols 0..95 = q (pre-scaled by 0.25), 96..191 = k; stride 200
  __shared__ __align__(16) short qk[64 * 200];   // 25600 B
  __shared__ __align__(16) short vT[96 * 72];    // v transposed [h*16+d][tok], 13824 B

  const int b = blockIdx.x;
  const int t = threadIdx.x;
  const int w = t >> 6;        // wave id = m-tile in phases 2/3
  const int l = t & 63;
  const int lm = l & 15;
  const int quad = l >> 4;

  // ---- mask hoist: head-invariant, float4 per nt (issue early) ----
  const float* maskp = mask + (size_t)(b & NW_MASK) * 4096 + (w * 16 + lm) * 64 + quad * 4;
  float mk[4][4];
#pragma unroll
  for (int nt = 0; nt < 4; ++nt) {
    const float4 m4 = *(const float4*)(maskp + nt * 16);
    mk[nt][0] = m4.x; mk[nt][1] = m4.y; mk[nt][2] = m4.z; mk[nt][3] = m4.w;
  }

  // ---- Phase 1: qkv = x @ Wqkv + b  (A-frags in regs, B-frags from ws) ----
  short8 afr[4][3];
#pragma unroll
  for (int mt = 0; mt < 4; ++mt)
#pragma unroll
    for (int ks = 0; ks < 3; ++ks) {
      const float* xp = x + ((size_t)b * 64 + mt * 16 + lm) * 96 + ks * 32 + quad * 8;
      const float4 u0 = *(const float4*)xp;
      const float4 u1 = *(const float4*)(xp + 4);
      short8 a;
      a[0] = f2bf(u0.x); a[1] = f2bf(u0.y); a[2] = f2bf(u0.z); a[3] = f2bf(u0.w);
      a[4] = f2bf(u1.x); a[5] = f2bf(u1.y); a[6] = f2bf(u1.z); a[7] = f2bf(u1.w);
      afr[mt][ks] = a;
    }

  const short8* wsq8 = (const short8*)wsq;
  // 36 work units = 18 ntiles x 2 m-halves, 9 per wave (balanced)
  for (int u = w * 9; u < w * 9 + 9; ++u) {
    const int nt = u >> 1, mh = (u & 1) * 2;
    short8 bfr[3];
#pragma unroll
    for (int ks = 0; ks < 3; ++ks) bfr[ks] = wsq8[(nt * 3 + ks) * 64 + l];
    const int c = nt * 16 + lm;
    const float bq = qkv_b[c];
    const float sc = (c < 96) ? 0.25f : 1.0f;  // q pre-scale, hd^-0.5 exact
#pragma unroll
    for (int mi = 0; mi < 2; ++mi) {
      const int mt = mh + mi;
      f32x4 acc = {bq, bq, bq, bq};
#pragma unroll
      for (int ks = 0; ks < 3; ++ks)
        acc = __builtin_amdgcn_mfma_f32_16x16x32_bf16(afr[mt][ks], bfr[ks], acc, 0, 0, 0);
#pragma unroll
      for (int i = 0; i < 4; ++i) {
        const int r = mt * 16 + quad * 4 + i;   // C-layout: row = quad*4+reg
        const short v = f2bf(acc[i] * sc);
        if (c < 192) qk[r * 200 + c] = v;
        else vT[(c - 192) * 72 + r] = v;
      }
    }
  }
  __syncthreads();   // the ONLY barrier: qk (k-cols) and vT are read cross-wave

  // ---- preload all 6 q B-frags (wave-private rows); q-cols then dead ----
  short8 qa6[6];
#pragma unroll
  for (int h = 0; h < 6; ++h) {
    short8 z = {0, 0, 0, 0, 0, 0, 0, 0};     // k>=16 zero-padded
    if (quad < 2)
      z = *(const short8*)&qk[(w * 16 + lm) * 200 + h * 16 + quad * 8];
    qa6[h] = z;
  }

  // ---- Phase 2: per-head attention (swapped QK^T), O accumulates in regs ----
  f32x4 oacc[6];
  const float* biasp = bias_f + (w * 16 + lm) * 64 + quad * 4;
  unsigned* prow = (unsigned*)&qk[(w * 16 + lm) * 200];  // P scratch, own row
#pragma unroll
  for (int h = 0; h < 6; ++h) {
    const f32x4 z4 = {0.f, 0.f, 0.f, 0.f};
    f32x4 lac[4];
#pragma unroll
    for (int nt = 0; nt < 4; ++nt) {
      short8 kb = {0, 0, 0, 0, 0, 0, 0, 0};
      if (quad < 2)
        kb = *(const short8*)&qk[(nt * 16 + lm) * 200 + 96 + h * 16 + quad * 8];
      // SWAPPED: D = K_nt * Q^T  ->  lac[nt][i] = S[w*16+lm][nt*16+quad*4+i]
      lac[nt] = __builtin_amdgcn_mfma_f32_16x16x32_bf16(kb, qa6[h], z4, 0, 0, 0);
    }
    // bias (float4) + mask (regs) + softmax over the row held in-lane/quads
    float lv[4][4];
    float mx = -3.0e38f;
#pragma unroll
    for (int nt = 0; nt < 4; ++nt) {
      const float4 b4 = *(const float4*)(biasp + h * 4096 + nt * 16);
      const float ba[4] = {b4.x, b4.y, b4.z, b4.w};
#pragma unroll
      for (int i = 0; i < 4; ++i) {
        lv[nt][i] = lac[nt][i] + ba[i] + mk[nt][i];
        mx = fmaxf(mx, lv[nt][i]);
      }
    }
    mx = fmaxf(mx, __shfl_xor(mx, 16));
    mx = fmaxf(mx, __shfl_xor(mx, 32));
    float sm = 0.f;
#pragma unroll
    for (int nt = 0; nt < 4; ++nt)
#pragma unroll
      for (int i = 0; i < 4; ++i) { lv[nt][i] = __expf(lv[nt][i] - mx); sm += lv[nt][i]; }
    sm += __shfl_xor(sm, 16);
    sm += __shfl_xor(sm, 32);
    const float inv = 1.0f / sm;
    // P -> q-cols of qk: row w*16+lm, cols nt*16+quad*4+{0..3}, packed u32
#pragma unroll
    for (int nt = 0; nt < 4; ++nt) {
      const unsigned w0 = cvt_pk_bf16(lv[nt][0] * inv, lv[nt][1] * inv);
      const unsigned w1 = cvt_pk_bf16(lv[nt][2] * inv, lv[nt][3] * inv);
      prow[(nt * 16 + quad * 4) >> 1] = w0;
      prow[(nt * 16 + quad * 4 + 2) >> 1] = w1;
    }
    // PV: O = P @ V, K=64 in 2 steps; same-wave LDS write->read (lgkmcnt only)
    f32x4 oa = {0.f, 0.f, 0.f, 0.f};
#pragma unroll
    for (int ks = 0; ks < 2; ++ks) {
      const short8 pa = *(const short8*)&qk[(w * 16 + lm) * 200 + ks * 32 + quad * 8];
      const short8 vb = *(const short8*)&vT[(h * 16 + lm) * 72 + ks * 32 + quad * 8];
      oa = __builtin_amdgcn_mfma_f32_16x16x32_bf16(pa, vb, oa, 0, 0, 0);
    }
    oacc[h] = oa;
  }

  // ---- Phase 3: out = concat(O) @ proj_w + b (concat in q-cols, wave-private) ----
  const int rbase = w * 16 + quad * 4;
#pragma unroll
  for (int h = 0; h < 6; ++h)
#pragma unroll
    for (int i = 0; i < 4; ++i)
      qk[(rbase + i) * 200 + h * 16 + lm] = f2bf(oacc[h][i]);

  short8 ca[3];
#pragma unroll
  for (int ks = 0; ks < 3; ++ks)
    ca[ks] = *(const short8*)&qk[(w * 16 + lm) * 200 + ks * 32 + quad * 8];

  const short8* wsp8 = (const short8*)wsp;
  float* outp = out + (size_t)b * 64 * 96;
#pragma unroll
  for (int nt = 0; nt < 6; ++nt) {
    short8 pw[3];
#pragma unroll
    for (int ks = 0; ks < 3; ++ks) pw[ks] = wsp8[(nt * 3 + ks) * 64 + l];
    const float bp = proj_b[nt * 16 + lm];
    f32x4 acc = {bp, bp, bp, bp};
#pragma unroll
    for (int ks = 0; ks < 3; ++ks)
      acc = __builtin_amdgcn_mfma_f32_16x16x32_bf16(ca[ks], pw[ks], acc, 0, 0, 0);
#pragma unroll
    for (int i = 0; i < 4; ++i)
      outp[(rbase + i) * 96 + nt * 16 + lm] = acc[i];
  }
}

extern "C" void kernel_launch(void* const* d_in, const int* in_sizes, int n_in,
                              void* d_out, int out_size, void* d_ws, size_t ws_size,
                              hipStream_t stream) {
  const float* x      = (const float*)d_in[0];
  const float* mask   = (const float*)d_in[1];
  const float* qkv_w  = (const float*)d_in[2];
  const float* qkv_b  = (const float*)d_in[3];
  const float* proj_w = (const float*)d_in[4];
  const float* proj_b = (const float*)d_in[5];
  const float* rpb    = (const float*)d_in[6];
  const int*   rel    = (const int*)d_in[7];

  float* bias_f = (float*)d_ws;                               // 98304 B
  short* wsq    = (short*)((char*)d_ws + 98304);              // 55296 B
  short* wsp    = (short*)((char*)d_ws + 98304 + 55296);      // 18432 B

  hipLaunchKernelGGL(prep_kernel, dim3(240), dim3(256), 0, stream,
                     qkv_w, proj_w, rpb, rel, bias_f, wsq, wsp);
  hipLaunchKernelGGL(winattn_kernel, dim3(8192), dim3(256), 0, stream,
                     x, mask, qkv_b, proj_b, bias_f, wsq, wsp, (float*)d_out);
}

// Round 5
// 476.117 us; speedup vs baseline: 1.7650x; 1.6208x over previous
//
#include <hip/hip_runtime.h>

typedef __attribute__((ext_vector_type(8))) short short8;
typedef __attribute__((ext_vector_type(4))) float f32x4;

#define NW_MASK 511

__device__ __forceinline__ short f2bf(float f) {
  unsigned u = __builtin_bit_cast(unsigned, f);
  u = (u + 0x7fffu + ((u >> 16) & 1u)) >> 16;  // RNE
  return (short)u;
}

__device__ __forceinline__ unsigned cvt_pk_bf16(float lo, float hi) {
  unsigned r;
  asm("v_cvt_pk_bf16_f32 %0, %1, %2" : "=v"(r) : "v"(lo), "v"(hi));
  return r;  // low 16 = bf16(lo), high 16 = bf16(hi), RNE
}

// ---------------------------------------------------------------------------
// Prep: gather rpb bias -> bias_f in COALESCED layout [h][nt][row][c4]:
//   element (h,row,col) at ((h*4 + col/16)*64 + row)*16 + col%16
// so the main kernel's per-(h,nt) float4 read is a contiguous 1KB wave burst.
// Also frag-swizzle qkv_w (96x288) and proj_w (96x96) into MFMA B-fragment-
// linear bf16 layout:
// ws*[ (nt*3+ks)*64 + lane ][ j ] = W[ ks*32 + (lane>>4)*8 + j ][ nt*16 + (lane&15) ]
// ---------------------------------------------------------------------------
__global__ void prep_kernel(const float* __restrict__ qkv_w,
                            const float* __restrict__ proj_w,
                            const float* __restrict__ rpb,
                            const int* __restrict__ rel_index,
                            float* __restrict__ bias_f,
                            short* __restrict__ wsq,
                            short* __restrict__ wsp) {
  int idx = blockIdx.x * 256 + threadIdx.x;
  if (idx < 24576) {                       // 6*64*64 bias gather, swizzled
    int c4  = idx & 15;
    int row = (idx >> 4) & 63;
    int nt  = (idx >> 10) & 3;
    int h   = idx >> 12;
    int col = nt * 16 + c4;
    bias_f[idx] = rpb[rel_index[row * 64 + col] * 6 + h];
  }
  int i2 = idx - 24576;
  if (i2 >= 0 && i2 < 27648) {             // 18 ntiles * 3 ksteps * 64 * 8
    int j = i2 & 7;
    int lane = (i2 >> 3) & 63;
    int frag = i2 >> 9;
    int ks = frag % 3, nt = frag / 3;
    int k = ks * 32 + (lane >> 4) * 8 + j;
    int n = nt * 16 + (lane & 15);
    wsq[i2] = f2bf(qkv_w[k * 288 + n]);
  }
  int i3 = i2 - 27648;
  if (i3 >= 0 && i3 < 9216) {              // 6 ntiles * 3 ksteps * 64 * 8
    int j = i3 & 7;
    int lane = (i3 >> 3) & 63;
    int frag = i3 >> 9;
    int ks = frag % 3, nt = frag / 3;
    int k = ks * 32 + (lane >> 4) * 8 + j;
    int n = nt * 16 + (lane & 15);
    wsp[i3] = f2bf(proj_w[k * 96 + n]);
  }
}

// ---------------------------------------------------------------------------
// Fused window attention: one block per window (8192), 256 threads (4 waves).
// LDS = qk (25600) + vT (13824) = 39424 B -> 4 blocks/CU with (256,4).
// QK^T is computed SWAPPED (S^T = mfma(K, Q)) so lane (quad,lm) holds
// S[row=w*16+lm][col=nt*16+quad*4+i]: bias/mask are float4 row-slices
// (bias layout pre-swizzled for 1KB coalesced bursts), softmax is 16 in-lane
// values + 2 shuffles, P round-trips through the dead q-columns of qk
// (wave-private rows). Phase 3 stages the f32 out-tile in qk (dead by then)
// and stores 6 x 1KB fully-coalesced dwordx4 bursts per wave — the previous
// 64B-fragment stores caused 3x write amplification + RMW fetch.
// ---------------------------------------------------------------------------
__global__ __launch_bounds__(256, 4) void winattn_kernel(
    const float* __restrict__ x, const float* __restrict__ mask,
    const float* __restrict__ qkv_b, const float* __restrict__ proj_b,
    const float* __restrict__ bias_f, const short* __restrict__ wsq,
    const short* __restrict__ wsp, float* __restrict__ out) {
  // qk: rows 64, cols 0..95 = q (pre-scaled by 0.25), 96..191 = k; stride 200
  __shared__ __align__(16) short qk[64 * 200];   // 25600 B
  __shared__ __align__(16) short vT[96 * 72];    // v transposed [h*16+d][tok], 13824 B

  const int b = blockIdx.x;
  const int t = threadIdx.x;
  const int w = t >> 6;        // wave id = m-tile in phases 2/3
  const int l = t & 63;
  const int lm = l & 15;
  const int quad = l >> 4;

  // ---- mask hoist: head-invariant, float4 per nt (issue early) ----
  const float* maskp = mask + (size_t)(b & NW_MASK) * 4096 + (w * 16 + lm) * 64 + quad * 4;
  float mk[4][4];
#pragma unroll
  for (int nt = 0; nt < 4; ++nt) {
    const float4 m4 = *(const float4*)(maskp + nt * 16);
    mk[nt][0] = m4.x; mk[nt][1] = m4.y; mk[nt][2] = m4.z; mk[nt][3] = m4.w;
  }

  // ---- Phase 1: qkv = x @ Wqkv + b  (A-frags in regs, B-frags from ws) ----
  short8 afr[4][3];
#pragma unroll
  for (int mt = 0; mt < 4; ++mt)
#pragma unroll
    for (int ks = 0; ks < 3; ++ks) {
      const float* xp = x + ((size_t)b * 64 + mt * 16 + lm) * 96 + ks * 32 + quad * 8;
      const float4 u0 = *(const float4*)xp;
      const float4 u1 = *(const float4*)(xp + 4);
      union { short8 s; unsigned u[4]; } a;
      a.u[0] = cvt_pk_bf16(u0.x, u0.y);
      a.u[1] = cvt_pk_bf16(u0.z, u0.w);
      a.u[2] = cvt_pk_bf16(u1.x, u1.y);
      a.u[3] = cvt_pk_bf16(u1.z, u1.w);
      afr[mt][ks] = a.s;
    }

  const short8* wsq8 = (const short8*)wsq;
  // wave w owns whole nt strips: starts {0,5,9,14} (counts 5,4,5,4).
  // Each weight fragment loaded ONCE and reused for all 4 m-tiles.
  const int nt0 = (w * 18 + 2) >> 2;
  const int nt1 = ((w + 1) * 18 + 2) >> 2;
  for (int nt = nt0; nt < nt1; ++nt) {
    short8 bfr[3];
#pragma unroll
    for (int ks = 0; ks < 3; ++ks) bfr[ks] = wsq8[(nt * 3 + ks) * 64 + l];
    const int c = nt * 16 + lm;
    const float bq = qkv_b[c];
    const float sc = (c < 96) ? 0.25f : 1.0f;  // q pre-scale, hd^-0.5 exact
#pragma unroll
    for (int mt = 0; mt < 4; ++mt) {
      f32x4 acc = {bq, bq, bq, bq};
#pragma unroll
      for (int ks = 0; ks < 3; ++ks)
        acc = __builtin_amdgcn_mfma_f32_16x16x32_bf16(afr[mt][ks], bfr[ks], acc, 0, 0, 0);
#pragma unroll
      for (int i = 0; i < 4; ++i) {
        const int r = mt * 16 + quad * 4 + i;   // C-layout: row = quad*4+reg
        const short v = f2bf(acc[i] * sc);
        if (c < 192) qk[r * 200 + c] = v;
        else vT[(c - 192) * 72 + r] = v;
      }
    }
  }
  __syncthreads();   // qk (k-cols) and vT are read cross-wave

  // ---- preload all 6 q B-frags (wave-private rows); q-cols then dead ----
  short8 qa6[6];
#pragma unroll
  for (int h = 0; h < 6; ++h) {
    short8 z = {0, 0, 0, 0, 0, 0, 0, 0};     // k>=16 zero-padded
    if (quad < 2)
      z = *(const short8*)&qk[(w * 16 + lm) * 200 + h * 16 + quad * 8];
    qa6[h] = z;
  }

  // ---- Phase 2: per-head attention (swapped QK^T), O accumulates in regs ----
  f32x4 oacc[6];
  const float* biasp = bias_f + (w * 16 + lm) * 16 + quad * 4;  // swizzled layout
  unsigned* prow = (unsigned*)&qk[(w * 16 + lm) * 200];  // P scratch, own row
#pragma unroll
  for (int h = 0; h < 6; ++h) {
    const f32x4 z4 = {0.f, 0.f, 0.f, 0.f};
    f32x4 lac[4];
#pragma unroll
    for (int nt = 0; nt < 4; ++nt) {
      short8 kb = {0, 0, 0, 0, 0, 0, 0, 0};
      if (quad < 2)
        kb = *(const short8*)&qk[(nt * 16 + lm) * 200 + 96 + h * 16 + quad * 8];
      // SWAPPED: D = K_nt * Q^T  ->  lac[nt][i] = S[w*16+lm][nt*16+quad*4+i]
      lac[nt] = __builtin_amdgcn_mfma_f32_16x16x32_bf16(kb, qa6[h], z4, 0, 0, 0);
    }
    // bias (coalesced float4) + mask (regs) + softmax over in-lane row
    float lv[4][4];
    float mx = -3.0e38f;
#pragma unroll
    for (int nt = 0; nt < 4; ++nt) {
      const float4 b4 = *(const float4*)(biasp + (h * 4 + nt) * 1024);
      const float ba[4] = {b4.x, b4.y, b4.z, b4.w};
#pragma unroll
      for (int i = 0; i < 4; ++i) {
        lv[nt][i] = lac[nt][i] + ba[i] + mk[nt][i];
        mx = fmaxf(mx, lv[nt][i]);
      }
    }
    mx = fmaxf(mx, __shfl_xor(mx, 16));
    mx = fmaxf(mx, __shfl_xor(mx, 32));
    float sm = 0.f;
#pragma unroll
    for (int nt = 0; nt < 4; ++nt)
#pragma unroll
      for (int i = 0; i < 4; ++i) { lv[nt][i] = __expf(lv[nt][i] - mx); sm += lv[nt][i]; }
    sm += __shfl_xor(sm, 16);
    sm += __shfl_xor(sm, 32);
    const float inv = 1.0f / sm;
    // P -> q-cols of qk: row w*16+lm, cols nt*16+quad*4+{0..3}, packed u32
#pragma unroll
    for (int nt = 0; nt < 4; ++nt) {
      const unsigned w0 = cvt_pk_bf16(lv[nt][0] * inv, lv[nt][1] * inv);
      const unsigned w1 = cvt_pk_bf16(lv[nt][2] * inv, lv[nt][3] * inv);
      prow[(nt * 16 + quad * 4) >> 1] = w0;
      prow[(nt * 16 + quad * 4 + 2) >> 1] = w1;
    }
    // PV: O = P @ V, K=64 in 2 steps; same-wave LDS write->read (lgkmcnt only)
    f32x4 oa = {0.f, 0.f, 0.f, 0.f};
#pragma unroll
    for (int ks = 0; ks < 2; ++ks) {
      const short8 pa = *(const short8*)&qk[(w * 16 + lm) * 200 + ks * 32 + quad * 8];
      const short8 vb = *(const short8*)&vT[(h * 16 + lm) * 72 + ks * 32 + quad * 8];
      oa = __builtin_amdgcn_mfma_f32_16x16x32_bf16(pa, vb, oa, 0, 0, 0);
    }
    oacc[h] = oa;
  }

  // ---- Phase 3: out = concat(O) @ proj_w + b ----
  const int rbase = w * 16 + quad * 4;
#pragma unroll
  for (int h = 0; h < 6; ++h)
#pragma unroll
    for (int i = 0; i < 4; ++i)
      qk[(rbase + i) * 200 + h * 16 + lm] = f2bf(oacc[h][i]);

  short8 ca[3];
#pragma unroll
  for (int ks = 0; ks < 3; ++ks)
    ca[ks] = *(const short8*)&qk[(w * 16 + lm) * 200 + ks * 32 + quad * 8];

  __syncthreads();   // all waves done with short-layout qk; reuse as f32 tile

  // Compute proj, stage f32 results in qk as flat [64][96] (wave-private
  // 6144B row-bands), then store 6 x 1KB fully-coalesced bursts per wave.
  float* olds = (float*)qk;
  const short8* wsp8 = (const short8*)wsp;
#pragma unroll
  for (int nt = 0; nt < 6; ++nt) {
    short8 pw[3];
#pragma unroll
    for (int ks = 0; ks < 3; ++ks) pw[ks] = wsp8[(nt * 3 + ks) * 64 + l];
    const float bp = proj_b[nt * 16 + lm];
    f32x4 acc = {bp, bp, bp, bp};
#pragma unroll
    for (int ks = 0; ks < 3; ++ks)
      acc = __builtin_amdgcn_mfma_f32_16x16x32_bf16(ca[ks], pw[ks], acc, 0, 0, 0);
#pragma unroll
    for (int i = 0; i < 4; ++i)
      olds[(rbase + i) * 96 + nt * 16 + lm] = acc[i];
  }
  // same-wave LDS write->read: lgkmcnt ordering only, no barrier needed
  const char* src = (const char*)qk + w * 6144;
  float* outp = out + (size_t)b * 6144 + w * 1536;
#pragma unroll
  for (int k = 0; k < 6; ++k) {
    const f32x4 v = *(const f32x4*)(src + k * 1024 + l * 16);
    *(f32x4*)(outp + k * 256 + l * 4) = v;
  }
}

extern "C" void kernel_launch(void* const* d_in, const int* in_sizes, int n_in,
                              void* d_out, int out_size, void* d_ws, size_t ws_size,
                              hipStream_t stream) {
  const float* x      = (const float*)d_in[0];
  const float* mask   = (const float*)d_in[1];
  const float* qkv_w  = (const float*)d_in[2];
  const float* qkv_b  = (const float*)d_in[3];
  const float* proj_w = (const float*)d_in[4];
  const float* proj_b = (const float*)d_in[5];
  const float* rpb    = (const float*)d_in[6];
  const int*   rel    = (const int*)d_in[7];

  float* bias_f = (float*)d_ws;                               // 98304 B
  short* wsq    = (short*)((char*)d_ws + 98304);              // 55296 B
  short* wsp    = (short*)((char*)d_ws + 98304 + 55296);      // 18432 B

  hipLaunchKernelGGL(prep_kernel, dim3(240), dim3(256), 0, stream,
                     qkv_w, proj_w, rpb, rel, bias_f, wsq, wsp);
  hipLaunchKernelGGL(winattn_kernel, dim3(8192), dim3(256), 0, stream,
                     x, mask, qkv_b, proj_b, bias_f, wsq, wsp, (float*)d_out);
}